// Round 8
// baseline (517.995 us; speedup 1.0000x reference)
//
#include <hip/hip_runtime.h>

typedef unsigned short u16;
typedef u16   u16x4 __attribute__((ext_vector_type(4)));
typedef u16   u16x8 __attribute__((ext_vector_type(8)));
typedef short s16x4 __attribute__((ext_vector_type(4)));
typedef __bf16 bf16x8 __attribute__((ext_vector_type(8)));
typedef float f32x4 __attribute__((ext_vector_type(4)));

#define LDP 264   // padded row stride (bf16 elems) for xb [64][256]
#define VTP 68    // padded row stride for vT [256][64]
#define OSP 260   // padded row stride (f32) for out staging [64][256]

__device__ __forceinline__ u16 f2b(float f) {
  union { float f; unsigned u; } c; c.f = f;
  return (u16)((c.u + 0x7fffu + ((c.u >> 16) & 1u)) >> 16);
}
__device__ __forceinline__ float b2f(u16 h) {
  union { unsigned u; float f; } c; c.u = ((unsigned)h) << 16;
  return c.f;
}
__device__ __forceinline__ bf16x8 ld16(const u16* p) {
  return __builtin_bit_cast(bf16x8, *reinterpret_cast<const u16x8*>(p));
}
__device__ __forceinline__ f32x4 z4() { f32x4 z; z[0]=0.f; z[1]=0.f; z[2]=0.f; z[3]=0.f; return z; }

// ---------------- prep ----------------
// ws layout (bytes):
//   0      : wq    bf16 768*256                (393216 B)
//   393216 : wp    bf16 256*256                (131072 B)
//   524288 : biasB bf16 [8][kt4][qt4][64][4]   (65536 B)
//   589824 : maskB bf16 [256][kt4][qt4][64][4] (2097152 B)
__global__ void prep_kernel(const float* __restrict__ qkv_w, const float* __restrict__ proj_w,
                            const float* __restrict__ mask, const float* __restrict__ table,
                            const int* __restrict__ rpi,
                            u16* __restrict__ wq, u16* __restrict__ wp,
                            u16* __restrict__ biasB, u16* __restrict__ maskB) {
  int i = blockIdx.x * 512 + threadIdx.x;
  if (i < 196608) { wq[i] = f2b(qkv_w[i]); return; }
  i -= 196608;
  if (i < 65536) { wp[i] = f2b(proj_w[i]); return; }
  i -= 65536;
  if (i < 32768) {  // biasB[h][kt][qt][lane][r]
    int r = i & 3, lane = (i >> 2) & 63, qt = (i >> 8) & 3, kt = (i >> 10) & 3, h = i >> 12;
    int qtok = qt * 16 + (lane & 15);
    int ktok = kt * 16 + (lane >> 4) * 4 + r;
    biasB[i] = f2b(table[rpi[qtok * 64 + ktok] * 8 + h]);
    return;
  }
  i -= 32768;
  if (i < 1048576) {  // maskB[w][kt][qt][lane][r]
    int r = i & 3, lane = (i >> 2) & 63, qt = (i >> 8) & 3, kt = (i >> 10) & 3, w = i >> 12;
    int qtok = qt * 16 + (lane & 15);
    int ktok = kt * 16 + (lane >> 4) * 4 + r;
    maskB[i] = f2b(mask[(w << 12) + qtok * 64 + ktok]);
  }
}

// ---------------- fused window attention: 1 block (512 thr)/window, 2 blk/CU --
__global__ __launch_bounds__(512, 4) void winattn_kernel(
    const float* __restrict__ x, const float* __restrict__ qkv_b,
    const float* __restrict__ proj_b, const float* __restrict__ logit_scale,
    const u16* __restrict__ wq, const u16* __restrict__ wp,
    const u16* __restrict__ biasB, const u16* __restrict__ maskB,
    float* __restrict__ out) {
  // one smem block, phase-overlaid:
  //   phases 0-3 : xb u16[64][LDP] @0 (33792 B) ; vT u16[256][VTP] @33792 (34816 B)
  //   epilogue   : outS f32[64][OSP] @0 (66560 B)
  __shared__ __align__(16) char smem[68608];
  u16  (*xb)[LDP]  = reinterpret_cast<u16(*)[LDP]>(smem);
  u16  (*vT)[VTP]  = reinterpret_cast<u16(*)[VTP]>(smem + 33792);
  float (*outS)[OSP] = reinterpret_cast<float(*)[OSP]>(smem);

  const int b    = blockIdx.x;
  const int tid  = threadIdx.x;
  const int h    = tid >> 6;    // wave = head
  const int lane = tid & 63;
  const int lr   = lane & 15;
  const int lg   = lane >> 4;

  // ---- Phase 0: stage x (fp32 -> bf16) into xb ----
  const f32x4* xg4 = reinterpret_cast<const f32x4*>(x + (size_t)b * 16384);
#pragma unroll
  for (int j = 0; j < 8; ++j) {
    int e4 = tid + j * 512;
    f32x4 v = xg4[e4];
    int e = e4 * 4, tok = e >> 8, c = e & 255;
    u16x4 hv;
    hv[0] = f2b(v[0]); hv[1] = f2b(v[1]); hv[2] = f2b(v[2]); hv[3] = f2b(v[3]);
    *reinterpret_cast<u16x4*>(&xb[tok][c]) = hv;
  }
  __syncthreads();

  // ---- Phase 1: QKV^T = W . X^T, wave h computes its own head's q,k,v ----
  // C layout per 16x16 tile: row(=feature) = lg*4+r, col(=token) = lr
  //  == the 16x16x16bf16_1k A/B fragment layout with k=d.
  s16x4 qf[2][4], kf[2][4];   // [d-tile][token-tile]

  // -- q pass --
  {
    f32x4 a0[4], a1[4];
#pragma unroll
    for (int tt = 0; tt < 4; ++tt) { a0[tt] = z4(); a1[tt] = z4(); }
    const u16* w0 = wq + (h * 32 + lr) * 256 + lg * 8;
#pragma unroll
    for (int ks = 0; ks < 8; ++ks) {
      bf16x8 wf0 = ld16(w0 + ks * 32);
      bf16x8 wf1 = ld16(w0 + 4096 + ks * 32);
#pragma unroll
      for (int tt = 0; tt < 4; ++tt) {
        bf16x8 xf = ld16(&xb[tt * 16 + lr][ks * 32 + lg * 8]);
        a0[tt] = __builtin_amdgcn_mfma_f32_16x16x32_bf16(wf0, xf, a0[tt], 0, 0, 0);
        a1[tt] = __builtin_amdgcn_mfma_f32_16x16x32_bf16(wf1, xf, a1[tt], 0, 0, 0);
      }
    }
    f32x4 bb0 = *reinterpret_cast<const f32x4*>(qkv_b + h * 32 + lg * 4);
    f32x4 bb1 = *reinterpret_cast<const f32x4*>(qkv_b + h * 32 + 16 + lg * 4);
    float lsv = __expf(fminf(logit_scale[h], 4.6051702f));
#pragma unroll
    for (int tt = 0; tt < 4; ++tt) {
      a0[tt] += bb0; a1[tt] += bb1;
      float ss = 0.f;
#pragma unroll
      for (int r = 0; r < 4; ++r) ss += a0[tt][r] * a0[tt][r] + a1[tt][r] * a1[tt][r];
      ss += __shfl_xor(ss, 16);
      ss += __shfl_xor(ss, 32);
      float inv = lsv / fmaxf(sqrtf(ss), 1e-12f);
#pragma unroll
      for (int r = 0; r < 4; ++r) {
        qf[0][tt][r] = (short)f2b(a0[tt][r] * inv);
        qf[1][tt][r] = (short)f2b(a1[tt][r] * inv);
      }
    }
  }
  // -- k pass --
  {
    f32x4 a0[4], a1[4];
#pragma unroll
    for (int tt = 0; tt < 4; ++tt) { a0[tt] = z4(); a1[tt] = z4(); }
    const u16* w0 = wq + (256 + h * 32 + lr) * 256 + lg * 8;
#pragma unroll
    for (int ks = 0; ks < 8; ++ks) {
      bf16x8 wf0 = ld16(w0 + ks * 32);
      bf16x8 wf1 = ld16(w0 + 4096 + ks * 32);
#pragma unroll
      for (int tt = 0; tt < 4; ++tt) {
        bf16x8 xf = ld16(&xb[tt * 16 + lr][ks * 32 + lg * 8]);
        a0[tt] = __builtin_amdgcn_mfma_f32_16x16x32_bf16(wf0, xf, a0[tt], 0, 0, 0);
        a1[tt] = __builtin_amdgcn_mfma_f32_16x16x32_bf16(wf1, xf, a1[tt], 0, 0, 0);
      }
    }
    f32x4 bb0 = *reinterpret_cast<const f32x4*>(qkv_b + 256 + h * 32 + lg * 4);
    f32x4 bb1 = *reinterpret_cast<const f32x4*>(qkv_b + 256 + h * 32 + 16 + lg * 4);
#pragma unroll
    for (int tt = 0; tt < 4; ++tt) {
      a0[tt] += bb0; a1[tt] += bb1;
      float ss = 0.f;
#pragma unroll
      for (int r = 0; r < 4; ++r) ss += a0[tt][r] * a0[tt][r] + a1[tt][r] * a1[tt][r];
      ss += __shfl_xor(ss, 16);
      ss += __shfl_xor(ss, 32);
      float inv = 1.0f / fmaxf(sqrtf(ss), 1e-12f);
#pragma unroll
      for (int r = 0; r < 4; ++r) {
        kf[0][tt][r] = (short)f2b(a0[tt][r] * inv);
        kf[1][tt][r] = (short)f2b(a1[tt][r] * inv);
      }
    }
  }
  // -- v pass -> vT in LDS --
  {
    f32x4 a0[4], a1[4];
#pragma unroll
    for (int tt = 0; tt < 4; ++tt) { a0[tt] = z4(); a1[tt] = z4(); }
    const u16* w0 = wq + (512 + h * 32 + lr) * 256 + lg * 8;
#pragma unroll
    for (int ks = 0; ks < 8; ++ks) {
      bf16x8 wf0 = ld16(w0 + ks * 32);
      bf16x8 wf1 = ld16(w0 + 4096 + ks * 32);
#pragma unroll
      for (int tt = 0; tt < 4; ++tt) {
        bf16x8 xf = ld16(&xb[tt * 16 + lr][ks * 32 + lg * 8]);
        a0[tt] = __builtin_amdgcn_mfma_f32_16x16x32_bf16(wf0, xf, a0[tt], 0, 0, 0);
        a1[tt] = __builtin_amdgcn_mfma_f32_16x16x32_bf16(wf1, xf, a1[tt], 0, 0, 0);
      }
    }
    f32x4 bb0 = *reinterpret_cast<const f32x4*>(qkv_b + 512 + h * 32 + lg * 4);
    f32x4 bb1 = *reinterpret_cast<const f32x4*>(qkv_b + 512 + h * 32 + 16 + lg * 4);
#pragma unroll
    for (int tt = 0; tt < 4; ++tt) {
      a0[tt] += bb0; a1[tt] += bb1;
#pragma unroll
      for (int r = 0; r < 4; ++r) {
        vT[h * 32 + lg * 4 + r][tt * 16 + lr] = f2b(a0[tt][r]);
        vT[h * 32 + 16 + lg * 4 + r][tt * 16 + lr] = f2b(a1[tt][r]);
      }
    }
  }
  __syncthreads();   // vT ready; all xb(x) reads done

  // ---- Phase 2: attention, one q-tile at a time (low register pressure) ----
  {
    const u16x4* bB = reinterpret_cast<const u16x4*>(biasB) + (size_t)h * 1024 + lane;
    const u16x4* mB = reinterpret_cast<const u16x4*>(maskB) + (size_t)(b & 255) * 1024 + lane;
#pragma unroll 1
    for (int qt = 0; qt < 4; ++qt) {
      f32x4 st[4];   // [ktile]; row=ktok(lg*4+r), col=qtok(lr)
#pragma unroll
      for (int kt = 0; kt < 4; ++kt) {
        f32x4 s = __builtin_amdgcn_mfma_f32_16x16x16bf16_1k(kf[0][kt], qf[0][qt], z4(), 0, 0, 0);
        st[kt] = __builtin_amdgcn_mfma_f32_16x16x16bf16_1k(kf[1][kt], qf[1][qt], s, 0, 0, 0);
        u16x4 b4 = bB[(kt * 4 + qt) * 64];
        u16x4 m4 = mB[(kt * 4 + qt) * 64];
#pragma unroll
        for (int r = 0; r < 4; ++r) st[kt][r] += b2f(b4[r]) + b2f(m4[r]);
      }
      // softmax over ktok: 16 local + 2 xor-shuffles
      float m = -1e30f;
#pragma unroll
      for (int kt = 0; kt < 4; ++kt)
#pragma unroll
        for (int r = 0; r < 4; ++r) m = fmaxf(m, st[kt][r]);
      m = fmaxf(m, __shfl_xor(m, 16));
      m = fmaxf(m, __shfl_xor(m, 32));
      float s = 0.f;
#pragma unroll
      for (int kt = 0; kt < 4; ++kt)
#pragma unroll
        for (int r = 0; r < 4; ++r) {
          float e = __expf(st[kt][r] - m);
          st[kt][r] = e; s += e;
        }
      s += __shfl_xor(s, 16);
      s += __shfl_xor(s, 32);
      float inv = 1.0f / s;
      s16x4 pa[4];
#pragma unroll
      for (int kt = 0; kt < 4; ++kt)
#pragma unroll
        for (int i = 0; i < 4; ++i) pa[kt][i] = (short)f2b(st[kt][i] * inv);

      // PV for this q-tile: O = P.V, V fragments from vT
      f32x4 o[2];
      o[0] = z4(); o[1] = z4();
#pragma unroll
      for (int dt = 0; dt < 2; ++dt)
#pragma unroll
        for (int kt = 0; kt < 4; ++kt) {
          s16x4 vf = *reinterpret_cast<const s16x4*>(&vT[h * 32 + dt * 16 + lr][kt * 16 + lg * 4]);
          o[dt] = __builtin_amdgcn_mfma_f32_16x16x16bf16_1k(pa[kt], vf, o[dt], 0, 0, 0);
        }
      // attn-out (bf16) -> xb (x no longer needed)
#pragma unroll
      for (int dt = 0; dt < 2; ++dt)
#pragma unroll
        for (int r = 0; r < 4; ++r) {
          int qtok = qt * 16 + lg * 4 + r;
          xb[qtok][h * 32 + dt * 16 + lr] = f2b(o[dt][r]);
        }
    }
  }
  __syncthreads();

  // ---- Phase 3: proj GEMM, accumulate in regs ----
  f32x4 acc[2][4];
  {
    const int nb0 = h * 32;
    const u16* wrow0 = wp + (nb0 + lr) * 256 + lg * 8;
    const u16* wrow1 = wrow0 + 4096;
#pragma unroll
    for (int j = 0; j < 2; ++j)
#pragma unroll
      for (int mt = 0; mt < 4; ++mt) acc[j][mt] = z4();
#pragma unroll
    for (int ks = 0; ks < 8; ++ks) {
      bf16x8 bf0 = ld16(wrow0 + ks * 32);
      bf16x8 bf1 = ld16(wrow1 + ks * 32);
#pragma unroll
      for (int mt = 0; mt < 4; ++mt) {
        bf16x8 af = ld16(&xb[mt * 16 + lr][ks * 32 + lg * 8]);
        acc[0][mt] = __builtin_amdgcn_mfma_f32_16x16x32_bf16(af, bf0, acc[0][mt], 0, 0, 0);
        acc[1][mt] = __builtin_amdgcn_mfma_f32_16x16x32_bf16(af, bf1, acc[1][mt], 0, 0, 0);
      }
    }
  }
  __syncthreads();   // all xb reads done; smem is reusable as outS

  // ---- Epilogue: stage fp32 result in LDS, then full-line coalesced store ----
  {
    const int nb0 = h * 32;
#pragma unroll
    for (int j = 0; j < 2; ++j) {
      const int colg = nb0 + j * 16 + lr;
      const float pbv = proj_b[colg];
#pragma unroll
      for (int mt = 0; mt < 4; ++mt)
#pragma unroll
        for (int r = 0; r < 4; ++r)
          outS[mt * 16 + lg * 4 + r][colg] = acc[j][mt][r] + pbv;
    }
  }
  __syncthreads();
  {
    float* og = out + (size_t)b * 16384;
#pragma unroll
    for (int j = 0; j < 8; ++j) {
      int e4 = tid + j * 512;
      int e = e4 * 4, row = e >> 8, c = e & 255;
      f32x4 v = *reinterpret_cast<const f32x4*>(&outS[row][c]);
      __builtin_nontemporal_store(v, reinterpret_cast<f32x4*>(og + e));
    }
  }
}

extern "C" void kernel_launch(void* const* d_in, const int* in_sizes, int n_in,
                              void* d_out, int out_size, void* d_ws, size_t ws_size,
                              hipStream_t stream) {
  const float* x    = (const float*)d_in[0];
  const float* mask = (const float*)d_in[1];
  const float* qw   = (const float*)d_in[2];
  const float* qb   = (const float*)d_in[3];
  const float* pw   = (const float*)d_in[4];
  const float* pb   = (const float*)d_in[5];
  const float* ls   = (const float*)d_in[6];
  const float* tab  = (const float*)d_in[7];
  const int*   rpi  = (const int*)d_in[8];

  char* ws = (char*)d_ws;
  u16* wqb   = (u16*)ws;                    // 768*256 bf16
  u16* wpb   = (u16*)(ws + 393216);         // 256*256 bf16
  u16* biasB = (u16*)(ws + 524288);         // [8][16][64][4] bf16
  u16* maskB = (u16*)(ws + 589824);         // [256][16][64][4] bf16

  prep_kernel<<<2624, 512, 0, stream>>>(qw, pw, mask, tab, rpi, wqb, wpb, biasB, maskB);
  winattn_kernel<<<2048, 512, 0, stream>>>(x, qb, pb, ls, wqb, wpb, biasB, maskB,
                                           (float*)d_out);
}

// Round 9
// 415.983 us; speedup vs baseline: 1.2452x; 1.2452x over previous
//
#include <hip/hip_runtime.h>

typedef unsigned short u16;
typedef u16   u16x4 __attribute__((ext_vector_type(4)));
typedef u16   u16x8 __attribute__((ext_vector_type(8)));
typedef short s16x4 __attribute__((ext_vector_type(4)));
typedef __bf16 bf16x8 __attribute__((ext_vector_type(8)));
typedef float f32x4 __attribute__((ext_vector_type(4)));

#define LDP 264   // padded row stride (bf16 elems) for xb [64][256]
#define VTP 68    // padded row stride for vT [256][64]
#define OSP 260   // padded row stride (f32) for out staging [64][256]

__device__ __forceinline__ u16 f2b(float f) {
  union { float f; unsigned u; } c; c.f = f;
  return (u16)((c.u + 0x7fffu + ((c.u >> 16) & 1u)) >> 16);
}
__device__ __forceinline__ float b2f(u16 h) {
  union { unsigned u; float f; } c; c.u = ((unsigned)h) << 16;
  return c.f;
}
__device__ __forceinline__ bf16x8 ld16(const u16* p) {
  return __builtin_bit_cast(bf16x8, *reinterpret_cast<const u16x8*>(p));
}
__device__ __forceinline__ f32x4 z4() { f32x4 z; z[0]=0.f; z[1]=0.f; z[2]=0.f; z[3]=0.f; return z; }

// ---------------- prep ----------------
// ws layout (bytes):
//   0      : wq    bf16 768*256                (393216 B)
//   393216 : wp    bf16 256*256                (131072 B)
//   524288 : biasB bf16 [8][kt4][qt4][64][4]   (65536 B)
//   589824 : maskB bf16 [256][kt4][qt4][64][4] (2097152 B)
__global__ void prep_kernel(const float* __restrict__ qkv_w, const float* __restrict__ proj_w,
                            const float* __restrict__ mask, const float* __restrict__ table,
                            const int* __restrict__ rpi,
                            u16* __restrict__ wq, u16* __restrict__ wp,
                            u16* __restrict__ biasB, u16* __restrict__ maskB) {
  int i = blockIdx.x * 512 + threadIdx.x;
  if (i < 196608) { wq[i] = f2b(qkv_w[i]); return; }
  i -= 196608;
  if (i < 65536) { wp[i] = f2b(proj_w[i]); return; }
  i -= 65536;
  if (i < 32768) {  // biasB[h][kt][qt][lane][r]
    int r = i & 3, lane = (i >> 2) & 63, qt = (i >> 8) & 3, kt = (i >> 10) & 3, h = i >> 12;
    int qtok = qt * 16 + (lane & 15);
    int ktok = kt * 16 + (lane >> 4) * 4 + r;
    biasB[i] = f2b(table[rpi[qtok * 64 + ktok] * 8 + h]);
    return;
  }
  i -= 32768;
  if (i < 1048576) {  // maskB[w][kt][qt][lane][r]
    int r = i & 3, lane = (i >> 2) & 63, qt = (i >> 8) & 3, kt = (i >> 10) & 3, w = i >> 12;
    int qtok = qt * 16 + (lane & 15);
    int ktok = kt * 16 + (lane >> 4) * 4 + r;
    maskB[i] = f2b(mask[(w << 12) + qtok * 64 + ktok]);
  }
}

// -------- fused window attention: 1 block (512 thr)/window, 256-VGPR budget --
__global__ __launch_bounds__(512, 2) void winattn_kernel(
    const float* __restrict__ x, const float* __restrict__ qkv_b,
    const float* __restrict__ proj_b, const float* __restrict__ logit_scale,
    const u16* __restrict__ wq, const u16* __restrict__ wp,
    const u16* __restrict__ biasB, const u16* __restrict__ maskB,
    float* __restrict__ out) {
  // one smem block, phase-overlaid:
  //   phases 0-3 : xb u16[64][LDP] @0 (33792 B) ; vT u16[256][VTP] @33792 (34816 B)
  //   epilogue   : outS f32[64][OSP] @0 (66560 B)
  __shared__ __align__(16) char smem[68608];
  u16  (*xb)[LDP]  = reinterpret_cast<u16(*)[LDP]>(smem);
  u16  (*vT)[VTP]  = reinterpret_cast<u16(*)[VTP]>(smem + 33792);
  float (*outS)[OSP] = reinterpret_cast<float(*)[OSP]>(smem);

  const int b    = blockIdx.x;
  const int tid  = threadIdx.x;
  const int h    = tid >> 6;    // wave = head
  const int lane = tid & 63;
  const int lr   = lane & 15;
  const int lg   = lane >> 4;

  // ---- Phase 0: stage x (fp32 -> bf16) into xb ----
  const f32x4* xg4 = reinterpret_cast<const f32x4*>(x + (size_t)b * 16384);
#pragma unroll
  for (int j = 0; j < 8; ++j) {
    int e4 = tid + j * 512;
    f32x4 v = xg4[e4];
    int e = e4 * 4, tok = e >> 8, c = e & 255;
    u16x4 hv;
    hv[0] = f2b(v[0]); hv[1] = f2b(v[1]); hv[2] = f2b(v[2]); hv[3] = f2b(v[3]);
    *reinterpret_cast<u16x4*>(&xb[tok][c]) = hv;
  }
  __syncthreads();

  // ---- Phase 1: QKV^T = W . X^T, wave h computes its own head's q,k,v ----
  // C layout per 16x16 tile: row(=feature) = lg*4+r, col(=token) = lr
  //  == the 16x16x16bf16_1k A/B fragment layout with k=d.
  s16x4 qf[2][4], kf[2][4];   // [d-tile][token-tile]

  // -- q pass --
  {
    f32x4 a0[4], a1[4];
#pragma unroll
    for (int tt = 0; tt < 4; ++tt) { a0[tt] = z4(); a1[tt] = z4(); }
    const u16* w0 = wq + (h * 32 + lr) * 256 + lg * 8;
#pragma unroll
    for (int ks = 0; ks < 8; ++ks) {
      bf16x8 wf0 = ld16(w0 + ks * 32);
      bf16x8 wf1 = ld16(w0 + 4096 + ks * 32);
#pragma unroll
      for (int tt = 0; tt < 4; ++tt) {
        bf16x8 xf = ld16(&xb[tt * 16 + lr][ks * 32 + lg * 8]);
        a0[tt] = __builtin_amdgcn_mfma_f32_16x16x32_bf16(wf0, xf, a0[tt], 0, 0, 0);
        a1[tt] = __builtin_amdgcn_mfma_f32_16x16x32_bf16(wf1, xf, a1[tt], 0, 0, 0);
      }
    }
    f32x4 bb0 = *reinterpret_cast<const f32x4*>(qkv_b + h * 32 + lg * 4);
    f32x4 bb1 = *reinterpret_cast<const f32x4*>(qkv_b + h * 32 + 16 + lg * 4);
    float lsv = __expf(fminf(logit_scale[h], 4.6051702f));
#pragma unroll
    for (int tt = 0; tt < 4; ++tt) {
      a0[tt] += bb0; a1[tt] += bb1;
      float ss = 0.f;
#pragma unroll
      for (int r = 0; r < 4; ++r) ss += a0[tt][r] * a0[tt][r] + a1[tt][r] * a1[tt][r];
      ss += __shfl_xor(ss, 16);
      ss += __shfl_xor(ss, 32);
      float inv = lsv / fmaxf(sqrtf(ss), 1e-12f);
#pragma unroll
      for (int r = 0; r < 4; ++r) {
        qf[0][tt][r] = (short)f2b(a0[tt][r] * inv);
        qf[1][tt][r] = (short)f2b(a1[tt][r] * inv);
      }
    }
  }
  // -- k pass --
  {
    f32x4 a0[4], a1[4];
#pragma unroll
    for (int tt = 0; tt < 4; ++tt) { a0[tt] = z4(); a1[tt] = z4(); }
    const u16* w0 = wq + (256 + h * 32 + lr) * 256 + lg * 8;
#pragma unroll
    for (int ks = 0; ks < 8; ++ks) {
      bf16x8 wf0 = ld16(w0 + ks * 32);
      bf16x8 wf1 = ld16(w0 + 4096 + ks * 32);
#pragma unroll
      for (int tt = 0; tt < 4; ++tt) {
        bf16x8 xf = ld16(&xb[tt * 16 + lr][ks * 32 + lg * 8]);
        a0[tt] = __builtin_amdgcn_mfma_f32_16x16x32_bf16(wf0, xf, a0[tt], 0, 0, 0);
        a1[tt] = __builtin_amdgcn_mfma_f32_16x16x32_bf16(wf1, xf, a1[tt], 0, 0, 0);
      }
    }
    f32x4 bb0 = *reinterpret_cast<const f32x4*>(qkv_b + 256 + h * 32 + lg * 4);
    f32x4 bb1 = *reinterpret_cast<const f32x4*>(qkv_b + 256 + h * 32 + 16 + lg * 4);
#pragma unroll
    for (int tt = 0; tt < 4; ++tt) {
      a0[tt] += bb0; a1[tt] += bb1;
      float ss = 0.f;
#pragma unroll
      for (int r = 0; r < 4; ++r) ss += a0[tt][r] * a0[tt][r] + a1[tt][r] * a1[tt][r];
      ss += __shfl_xor(ss, 16);
      ss += __shfl_xor(ss, 32);
      float inv = 1.0f / fmaxf(sqrtf(ss), 1e-12f);
#pragma unroll
      for (int r = 0; r < 4; ++r) {
        kf[0][tt][r] = (short)f2b(a0[tt][r] * inv);
        kf[1][tt][r] = (short)f2b(a1[tt][r] * inv);
      }
    }
  }
  // -- v pass -> vT in LDS --
  {
    f32x4 a0[4], a1[4];
#pragma unroll
    for (int tt = 0; tt < 4; ++tt) { a0[tt] = z4(); a1[tt] = z4(); }
    const u16* w0 = wq + (512 + h * 32 + lr) * 256 + lg * 8;
#pragma unroll
    for (int ks = 0; ks < 8; ++ks) {
      bf16x8 wf0 = ld16(w0 + ks * 32);
      bf16x8 wf1 = ld16(w0 + 4096 + ks * 32);
#pragma unroll
      for (int tt = 0; tt < 4; ++tt) {
        bf16x8 xf = ld16(&xb[tt * 16 + lr][ks * 32 + lg * 8]);
        a0[tt] = __builtin_amdgcn_mfma_f32_16x16x32_bf16(wf0, xf, a0[tt], 0, 0, 0);
        a1[tt] = __builtin_amdgcn_mfma_f32_16x16x32_bf16(wf1, xf, a1[tt], 0, 0, 0);
      }
    }
    f32x4 bb0 = *reinterpret_cast<const f32x4*>(qkv_b + 512 + h * 32 + lg * 4);
    f32x4 bb1 = *reinterpret_cast<const f32x4*>(qkv_b + 512 + h * 32 + 16 + lg * 4);
#pragma unroll
    for (int tt = 0; tt < 4; ++tt) {
      a0[tt] += bb0; a1[tt] += bb1;
#pragma unroll
      for (int r = 0; r < 4; ++r) {
        vT[h * 32 + lg * 4 + r][tt * 16 + lr] = f2b(a0[tt][r]);
        vT[h * 32 + 16 + lg * 4 + r][tt * 16 + lr] = f2b(a1[tt][r]);
      }
    }
  }
  __syncthreads();   // vT ready; all xb(x) reads done

  // ---- Phase 2: attention, per q-tile, fully unrolled (static reg indices) --
  {
    const u16x4* bB = reinterpret_cast<const u16x4*>(biasB) + (size_t)h * 1024 + lane;
    const u16x4* mB = reinterpret_cast<const u16x4*>(maskB) + (size_t)(b & 255) * 1024 + lane;
#pragma unroll
    for (int qt = 0; qt < 4; ++qt) {
      f32x4 st[4];   // [ktile]; row=ktok(lg*4+r), col=qtok(lr)
#pragma unroll
      for (int kt = 0; kt < 4; ++kt) {
        f32x4 s = __builtin_amdgcn_mfma_f32_16x16x16bf16_1k(kf[0][kt], qf[0][qt], z4(), 0, 0, 0);
        st[kt] = __builtin_amdgcn_mfma_f32_16x16x16bf16_1k(kf[1][kt], qf[1][qt], s, 0, 0, 0);
        u16x4 b4 = bB[(kt * 4 + qt) * 64];
        u16x4 m4 = mB[(kt * 4 + qt) * 64];
#pragma unroll
        for (int r = 0; r < 4; ++r) st[kt][r] += b2f(b4[r]) + b2f(m4[r]);
      }
      // softmax over ktok: 16 local + 2 xor-shuffles
      float m = -1e30f;
#pragma unroll
      for (int kt = 0; kt < 4; ++kt)
#pragma unroll
        for (int r = 0; r < 4; ++r) m = fmaxf(m, st[kt][r]);
      m = fmaxf(m, __shfl_xor(m, 16));
      m = fmaxf(m, __shfl_xor(m, 32));
      float s = 0.f;
#pragma unroll
      for (int kt = 0; kt < 4; ++kt)
#pragma unroll
        for (int r = 0; r < 4; ++r) {
          float e = __expf(st[kt][r] - m);
          st[kt][r] = e; s += e;
        }
      s += __shfl_xor(s, 16);
      s += __shfl_xor(s, 32);
      float inv = 1.0f / s;
      s16x4 pa[4];
#pragma unroll
      for (int kt = 0; kt < 4; ++kt)
#pragma unroll
        for (int i = 0; i < 4; ++i) pa[kt][i] = (short)f2b(st[kt][i] * inv);

      // PV for this q-tile: O = P.V, V fragments from vT
      f32x4 o[2];
      o[0] = z4(); o[1] = z4();
#pragma unroll
      for (int dt = 0; dt < 2; ++dt)
#pragma unroll
        for (int kt = 0; kt < 4; ++kt) {
          s16x4 vf = *reinterpret_cast<const s16x4*>(&vT[h * 32 + dt * 16 + lr][kt * 16 + lg * 4]);
          o[dt] = __builtin_amdgcn_mfma_f32_16x16x16bf16_1k(pa[kt], vf, o[dt], 0, 0, 0);
        }
      // attn-out (bf16) -> xb (x no longer needed)
#pragma unroll
      for (int dt = 0; dt < 2; ++dt)
#pragma unroll
        for (int r = 0; r < 4; ++r) {
          int qtok = qt * 16 + lg * 4 + r;
          xb[qtok][h * 32 + dt * 16 + lr] = f2b(o[dt][r]);
        }
    }
  }
  __syncthreads();

  // ---- Phase 3: proj GEMM, accumulate in regs ----
  f32x4 acc[2][4];
  {
    const int nb0 = h * 32;
    const u16* wrow0 = wp + (nb0 + lr) * 256 + lg * 8;
    const u16* wrow1 = wrow0 + 4096;
#pragma unroll
    for (int j = 0; j < 2; ++j)
#pragma unroll
      for (int mt = 0; mt < 4; ++mt) acc[j][mt] = z4();
#pragma unroll
    for (int ks = 0; ks < 8; ++ks) {
      bf16x8 bf0 = ld16(wrow0 + ks * 32);
      bf16x8 bf1 = ld16(wrow1 + ks * 32);
#pragma unroll
      for (int mt = 0; mt < 4; ++mt) {
        bf16x8 af = ld16(&xb[mt * 16 + lr][ks * 32 + lg * 8]);
        acc[0][mt] = __builtin_amdgcn_mfma_f32_16x16x32_bf16(af, bf0, acc[0][mt], 0, 0, 0);
        acc[1][mt] = __builtin_amdgcn_mfma_f32_16x16x32_bf16(af, bf1, acc[1][mt], 0, 0, 0);
      }
    }
  }
  __syncthreads();   // all xb reads done; smem is reusable as outS

  // ---- Epilogue: stage fp32 result in LDS, then full-line coalesced store ----
  {
    const int nb0 = h * 32;
#pragma unroll
    for (int j = 0; j < 2; ++j) {
      const int colg = nb0 + j * 16 + lr;
      const float pbv = proj_b[colg];
#pragma unroll
      for (int mt = 0; mt < 4; ++mt)
#pragma unroll
        for (int r = 0; r < 4; ++r)
          outS[mt * 16 + lg * 4 + r][colg] = acc[j][mt][r] + pbv;
    }
  }
  __syncthreads();
  {
    float* og = out + (size_t)b * 16384;
#pragma unroll
    for (int j = 0; j < 8; ++j) {
      int e4 = tid + j * 512;
      int e = e4 * 4, row = e >> 8, c = e & 255;
      f32x4 v = *reinterpret_cast<const f32x4*>(&outS[row][c]);
      __builtin_nontemporal_store(v, reinterpret_cast<f32x4*>(og + e));
    }
  }
}

extern "C" void kernel_launch(void* const* d_in, const int* in_sizes, int n_in,
                              void* d_out, int out_size, void* d_ws, size_t ws_size,
                              hipStream_t stream) {
  const float* x    = (const float*)d_in[0];
  const float* mask = (const float*)d_in[1];
  const float* qw   = (const float*)d_in[2];
  const float* qb   = (const float*)d_in[3];
  const float* pw   = (const float*)d_in[4];
  const float* pb   = (const float*)d_in[5];
  const float* ls   = (const float*)d_in[6];
  const float* tab  = (const float*)d_in[7];
  const int*   rpi  = (const int*)d_in[8];

  char* ws = (char*)d_ws;
  u16* wqb   = (u16*)ws;                    // 768*256 bf16
  u16* wpb   = (u16*)(ws + 393216);         // 256*256 bf16
  u16* biasB = (u16*)(ws + 524288);         // [8][16][64][4] bf16
  u16* maskB = (u16*)(ws + 589824);         // [256][16][64][4] bf16

  prep_kernel<<<2624, 512, 0, stream>>>(qw, pw, mask, tab, rpi, wqb, wpb, biasB, maskB);
  winattn_kernel<<<2048, 512, 0, stream>>>(x, qb, pb, ls, wqb, wpb, biasB, maskB,
                                           (float*)d_out);
}